// Round 5
// baseline (293.214 us; speedup 1.0000x reference)
//
#include <hip/hip_runtime.h>
#include <hip/hip_bf16.h>
#include <math.h>

// Problem constants (fixed by setup_inputs): B=2, Cin=Cout=64, H=W=128
#define HWSZ 16384   // H*W
#define NPIX 32768   // B*H*W
#define ROWB 2064    // LDS row stride bytes: 1024 bf16 + 8 pad

typedef __attribute__((ext_vector_type(8))) short bf16x8;
typedef __attribute__((ext_vector_type(4))) float f32x4;

__device__ __forceinline__ unsigned pk2(float x, float y) {
    __hip_bfloat16 bx = __float2bfloat16(x), by = __float2bfloat16(y);
    unsigned short ux, uy;
    __builtin_memcpy(&ux, &bx, 2);
    __builtin_memcpy(&uy, &by, 2);
    return (unsigned)ux | ((unsigned)uy << 16);
}

// ---------------- k_pool: per-(b,c) mean over H,W ----------------
__global__ __launch_bounds__(1024) void k_pool(const float* __restrict__ inp,
                                               float* __restrict__ pooled) {
    int bc = blockIdx.x;
    const float4* p4 = (const float4*)(inp + (size_t)bc * HWSZ);
    float s = 0.f;
    for (int i = threadIdx.x; i < HWSZ / 4; i += 1024) {
        float4 v = p4[i];
        s += v.x + v.y + v.z + v.w;
    }
#pragma unroll
    for (int off = 32; off; off >>= 1) s += __shfl_down(s, off, 64);
    __shared__ float ls[16];
    if ((threadIdx.x & 63) == 0) ls[threadIdx.x >> 6] = s;
    __syncthreads();
    if (threadIdx.x == 0) {
        float t = 0.f;
#pragma unroll
        for (int i = 0; i < 16; i++) t += ls[i];
        pooled[bc] = t * (1.0f / 16384.0f);
    }
}

// ---------------- k_r: alpha[8] from sigmoid(fc) ----------------
__global__ void k_r(const float* __restrict__ pooled,
                    const float* __restrict__ fc_w,
                    const float* __restrict__ fc_b,
                    float* __restrict__ alpha) {
    int c = threadIdx.x;
    float s = pooled[c] + pooled[64 + c];
#pragma unroll
    for (int j = 0; j < 4; j++) {
        float v = s * fc_w[j * 64 + c];
#pragma unroll
        for (int off = 32; off; off >>= 1) v += __shfl_down(v, off, 64);
        if (c == 0) {
            float z = v + fc_b[j];
            float r = 1.0f / (1.0f + expf(-z));
            alpha[2 * j]     = r;
            alpha[2 * j + 1] = 1.0f;
        }
    }
}

// ---------------- k_wfrag: weight -> MFMA A-fragment order, bf16 -------------
// Afrag[((ot*32 + s)*64 + lane)*8 + e]; lane=(quad<<4)|m; A[m][k], k=s*32+quad*8+e
// k -> (c = k>>4, j = k&15), zero for j>=9. 65536 elements.
__global__ __launch_bounds__(256) void k_wfrag(const float* __restrict__ w,
                                               __hip_bfloat16* __restrict__ Afrag) {
    int i = blockIdx.x * 256 + threadIdx.x;   // 0..65535
    int ot = i >> 14, s = (i >> 9) & 31, l = (i >> 3) & 63, e = i & 7;
    int m = l & 15, quad = l >> 4;
    int o = ot * 16 + m;
    int k = s * 32 + quad * 8 + e;
    int c = k >> 4, j = k & 15;
    float v = (j < 9) ? w[o * 576 + c * 9 + j] : 0.0f;
    Afrag[i] = __float2bfloat16(v);
}

// ---------------- k_fused: taps (phase 0) + sample (phase 1) + MFMA (phase 2)
// Block = 16 px. Phase 0: compute per-pixel bilinear taps + blend coefs in LDS.
// Phase 1: thread (pl=tid&15, cq=tid>>4) samples 4 channels into
// E_lds[px][k=c*16+j] (bf16, zero-padded). Phase 2: wave wv = o-tile, 32 MFMA.
__global__ __launch_bounds__(256, 4) void k_fused(const float* __restrict__ inp,
                                                  const float* __restrict__ off,
                                                  const float* __restrict__ msk,
                                                  const float* __restrict__ w8,
                                                  const float* __restrict__ alpha,
                                                  const __hip_bfloat16* __restrict__ Afrag,
                                                  const float* __restrict__ bias,
                                                  float* __restrict__ out) {
    __shared__ __attribute__((aligned(16))) char els[16 * ROWB];
    __shared__ float tapW[36][16];
    __shared__ int   tapIP[9][16];
    __shared__ float tapU[8][16];
    __shared__ float tapVV[4][16];

    const int tid = threadIdx.x;
    const int p0t = blockIdx.x * 16;

    // ---------------- phase 0: taps into LDS ----------------
    if (tid < 144) {
        int px = tid & 15, k = tid >> 4;           // k uniform per 16-thread row
        int p = p0t + px;
        int b = p >> 14, sp = p & (HWSZ - 1);
        int h = sp >> 7, w = sp & 127;
        float oy = off[(size_t)b * 18 * HWSZ + (2 * k) * HWSZ + sp];
        float ox = off[(size_t)b * 18 * HWSZ + (2 * k + 1) * HWSZ + sp];
        float m  = msk[(size_t)b * 9 * HWSZ + k * HWSZ + sp];
        float py = (float)(h + k / 3 - 1) + oy;
        float px_ = (float)(w + k % 3 - 1) + ox;
        float fy = floorf(py), fx = floorf(px_);
        float ly = py - fy, lx = px_ - fx;
        int iy0 = (int)fy, ix0 = (int)fx;
        int iy1 = iy0 + 1, ix1 = ix0 + 1;
        bool vy0 = ((unsigned)iy0 < 128u), vy1 = ((unsigned)iy1 < 128u);
        bool vx0 = ((unsigned)ix0 < 128u), vx1 = ((unsigned)ix1 < 128u);
        float hy = 1.0f - ly, hx = 1.0f - lx;
        tapW[k * 4 + 0][px] = (vy0 && vx0) ? hy * hx * m : 0.0f;
        tapW[k * 4 + 1][px] = (vy0 && vx1) ? hy * lx * m : 0.0f;
        tapW[k * 4 + 2][px] = (vy1 && vx0) ? ly * hx * m : 0.0f;
        tapW[k * 4 + 3][px] = (vy1 && vx1) ? ly * lx * m : 0.0f;
        int cy0 = min(max(iy0, 0), 127), cy1 = min(max(iy1, 0), 127);
        int cx0 = min(max(ix0, 0), 127), cx1 = min(max(ix1, 0), 127);
        int a  = min(cx0, 126);
        int s0 = cx0 - a, s1 = cx1 - a, dy = cy1 - cy0;
        tapIP[k][px] = (cy0 * 128 + a) | (dy << 14) | (s0 << 15) | (s1 << 16);
    }
    if (tid < 128) {
        int px = tid & 15, q = tid >> 4;
        int p = p0t + px;
        int b = p >> 14, sp = p & (HWSZ - 1);
        float x = w8[(size_t)b * 8 * HWSZ + q * HWSZ + sp];
        float a = alpha[q];
        tapU[q][px] = x * a;
        if ((q & 1) == 0) tapVV[q >> 1][px] = x * (1.0f - a);
    }
    __syncthreads();

    // ---------------- phase 1: sample 4 channels ----------------
    {
        const int pl = tid & 15;
        const int cq = tid >> 4;
        const int p  = p0t + pl;
        const int b  = p >> 14;

        float W00[9], W01[9], W10[9], W11[9];
        int   IPK[9];
#pragma unroll
        for (int k = 0; k < 9; k++) {
            W00[k] = tapW[k * 4 + 0][pl];
            W01[k] = tapW[k * 4 + 1][pl];
            W10[k] = tapW[k * 4 + 2][pl];
            W11[k] = tapW[k * 4 + 3][pl];
            IPK[k] = tapIP[k][pl];
        }
        float u[8], vv[4];
#pragma unroll
        for (int q = 0; q < 8; q++) u[q] = tapU[q][pl];
#pragma unroll
        for (int q = 0; q < 4; q++) vv[q] = tapVV[q][pl];

        constexpr int PINV[8][9] = {
            {0,1,2,3,4,5,6,7,8},
            {1,2,5,0,4,8,3,6,7},
            {2,5,8,1,4,7,0,3,6},
            {5,8,7,2,4,6,1,0,3},
            {8,7,6,5,4,3,2,1,0},
            {7,6,3,8,4,0,5,2,1},
            {6,3,0,7,4,1,8,5,2},
            {3,0,1,6,4,2,7,8,5}};
        const float SA = 0.5f, SB = 0.20710678f, SC = 0.08578644f;

        const float* ipb = inp + (size_t)(b * 64 + cq * 4) * HWSZ;
#pragma unroll 1
        for (int half = 0; half < 2; half++) {
            float sam2[2][9];
            // two channels' gathers issued together: 36 independent 8B loads
#pragma unroll
            for (int cc = 0; cc < 2; cc++) {
                const float* ip = ipb + (size_t)(half * 2 + cc) * HWSZ;
#pragma unroll
                for (int k = 0; k < 9; k++) {
                    int pk   = IPK[k];
                    int base = pk & 16383;
                    int dy   = (pk >> 14) & 1;
                    int s0   = (pk >> 15) & 1;
                    int s1   = (pk >> 16) & 1;
                    float2 fa, fb;
                    __builtin_memcpy(&fa, ip + base, sizeof(float2));
                    __builtin_memcpy(&fb, ip + base + (dy << 7), sizeof(float2));
                    float v00 = s0 ? fa.y : fa.x;
                    float v01 = s1 ? fa.y : fa.x;
                    float v10 = s0 ? fb.y : fb.x;
                    float v11 = s1 ? fb.y : fb.x;
                    sam2[cc][k] = W00[k] * v00 + W01[k] * v01 +
                                  W10[k] * v10 + W11[k] * v11;
                }
            }
#pragma unroll
            for (int cc = 0; cc < 2; cc++) {
                float* sam = sam2[cc];
                float A[9], Bv[9];
#pragma unroll
                for (int t = 0; t < 9; t++) {
                    float a = 0.f, bb = 0.f;
#pragma unroll
                    for (int q = 0; q < 8; q++) a += u[q] * sam[PINV[q][t]];
#pragma unroll
                    for (int i = 0; i < 4; i++) bb += vv[i] * sam[PINV[2 * i][t]];
                    A[t] = a; Bv[t] = bb;
                }
                float Ev[9];
                Ev[0] = SA * A[0] + Bv[0];
                Ev[1] = A[1] + SB * (A[0] + A[2]) + Bv[1];
                Ev[2] = SA * A[2] + Bv[2];
                Ev[3] = A[3] + SB * (A[0] + A[6]) + Bv[3];
                Ev[4] = A[4] + SC * (A[0] + A[2] + A[6] + A[8]) + Bv[4];
                Ev[5] = A[5] + SB * (A[2] + A[8]) + Bv[5];
                Ev[6] = SA * A[6] + Bv[6];
                Ev[7] = A[7] + SB * (A[6] + A[8]) + Bv[7];
                Ev[8] = SA * A[8] + Bv[8];

                int c = cq * 4 + half * 2 + cc;
                uint4 q0, q1;
                q0.x = pk2(Ev[0], Ev[1]);
                q0.y = pk2(Ev[2], Ev[3]);
                q0.z = pk2(Ev[4], Ev[5]);
                q0.w = pk2(Ev[6], Ev[7]);
                q1.x = pk2(Ev[8], 0.0f);
                q1.y = 0u; q1.z = 0u; q1.w = 0u;
                char* dst = els + pl * ROWB + c * 32;
                *(uint4*)dst = q0;
                *(uint4*)(dst + 16) = q1;
            }
        }
    }
    __syncthreads();

    // ---------------- phase 2: MFMA GEMM ----------------
    const int l    = tid & 63;
    const int wv   = tid >> 6;            // o-tile
    const int pl16 = l & 15;
    const int quad = l >> 4;

    const bf16x8* Ap = (const bf16x8*)Afrag;
    const bf16x8* Bp = (const bf16x8*)(els + pl16 * ROWB + quad * 16);

    f32x4 acc = (f32x4){0.f, 0.f, 0.f, 0.f};
    size_t ai = (size_t)(wv * 32) * 64 + l;
#pragma unroll 4
    for (int s = 0; s < 32; s++) {
        bf16x8 av = Ap[ai + (size_t)s * 64];
        bf16x8 bv = Bp[s * 4];
        acc = __builtin_amdgcn_mfma_f32_16x16x32_bf16(av, bv, acc, 0, 0, 0);
    }

    // epilogue: D row = quad*4 + r (o-offset), col = pl16 (px)
    const int pp  = p0t + pl16;
    const int bb  = pp >> 14;
    const int spp = pp & (HWSZ - 1);
    float w8v[8];
#pragma unroll
    for (int q = 0; q < 8; q++) w8v[q] = w8[(size_t)bb * 8 * HWSZ + q * HWSZ + spp];

#pragma unroll
    for (int r = 0; r < 4; r++) {
        int o = wv * 16 + quad * 4 + r;
        float bv = 0.f;
#pragma unroll
        for (int q = 0; q < 8; q++) bv += w8v[q] * bias[q * 64 + o];
        out[(size_t)(bb * 64 + o) * HWSZ + spp] = acc[r] + bv;
    }
}

// ---------------- Launch ----------------
extern "C" void kernel_launch(void* const* d_in, const int* in_sizes, int n_in,
                              void* d_out, int out_size, void* d_ws, size_t ws_size,
                              hipStream_t stream) {
    const float* input  = (const float*)d_in[0];
    const float* offset = (const float*)d_in[1];
    const float* mask   = (const float*)d_in[2];
    const float* w_c8   = (const float*)d_in[3];
    const float* weight = (const float*)d_in[4];
    const float* bias   = (const float*)d_in[5];
    const float* fc_w   = (const float*)d_in[6];
    const float* fc_b   = (const float*)d_in[7];
    float* out = (float*)d_out;
    float* wsf = (float*)d_ws;

    // ws layout (float units):
    //   Afrag bf16 [65536]   @ 0        (32768 f)
    //   pooled [128]         @ 32768
    //   alpha  [8]           @ 32896
    __hip_bfloat16* Afrag = (__hip_bfloat16*)wsf;
    float* pooled = wsf + 32768;
    float* alpha  = wsf + 32896;

    k_pool<<<dim3(128), dim3(1024), 0, stream>>>(input, pooled);
    k_r<<<dim3(1), dim3(64), 0, stream>>>(pooled, fc_w, fc_b, alpha);
    k_wfrag<<<dim3(256), dim3(256), 0, stream>>>(weight, Afrag);
    k_fused<<<dim3(2048), dim3(256), 0, stream>>>(input, offset, mask, w_c8,
                                                  alpha, Afrag, bias, out);
}

// Round 6
// 141.948 us; speedup vs baseline: 2.0656x; 2.0656x over previous
//
#include <hip/hip_runtime.h>
#include <hip/hip_bf16.h>
#include <math.h>

// Problem constants (fixed by setup_inputs): B=2, Cin=Cout=64, H=W=128
#define HWSZ 16384   // H*W
#define NPIX 32768   // B*H*W
#define ROWB 2064    // LDS row stride bytes: 1024 bf16 + 8 pad

typedef __attribute__((ext_vector_type(8))) short bf16x8;
typedef __attribute__((ext_vector_type(4))) float f32x4;

__device__ __forceinline__ unsigned pk2(float x, float y) {
    __hip_bfloat16 bx = __float2bfloat16(x), by = __float2bfloat16(y);
    unsigned short ux, uy;
    __builtin_memcpy(&ux, &bx, 2);
    __builtin_memcpy(&uy, &by, 2);
    return (unsigned)ux | ((unsigned)uy << 16);
}

// ---------------- k_pool: per-(b,c) mean over H,W ----------------
__global__ __launch_bounds__(1024) void k_pool(const float* __restrict__ inp,
                                               float* __restrict__ pooled) {
    int bc = blockIdx.x;
    const float4* p4 = (const float4*)(inp + (size_t)bc * HWSZ);
    float s = 0.f;
    for (int i = threadIdx.x; i < HWSZ / 4; i += 1024) {
        float4 v = p4[i];
        s += v.x + v.y + v.z + v.w;
    }
#pragma unroll
    for (int off = 32; off; off >>= 1) s += __shfl_down(s, off, 64);
    __shared__ float ls[16];
    if ((threadIdx.x & 63) == 0) ls[threadIdx.x >> 6] = s;
    __syncthreads();
    if (threadIdx.x == 0) {
        float t = 0.f;
#pragma unroll
        for (int i = 0; i < 16; i++) t += ls[i];
        pooled[bc] = t * (1.0f / 16384.0f);
    }
}

// ---------------- k_r: alpha[8] from sigmoid(fc) ----------------
__global__ void k_r(const float* __restrict__ pooled,
                    const float* __restrict__ fc_w,
                    const float* __restrict__ fc_b,
                    float* __restrict__ alpha) {
    int c = threadIdx.x;
    float s = pooled[c] + pooled[64 + c];
#pragma unroll
    for (int j = 0; j < 4; j++) {
        float v = s * fc_w[j * 64 + c];
#pragma unroll
        for (int off = 32; off; off >>= 1) v += __shfl_down(v, off, 64);
        if (c == 0) {
            float z = v + fc_b[j];
            float r = 1.0f / (1.0f + expf(-z));
            alpha[2 * j]     = r;
            alpha[2 * j + 1] = 1.0f;
        }
    }
}

// ---------------- k_wfrag: weight -> MFMA A-fragment order, bf16 -------------
// Afrag[((ot*32 + s)*64 + lane)*8 + e]; lane=(quad<<4)|m; A[m][k], k=s*32+quad*8+e
// k -> (c = k>>4, j = k&15), zero for j>=9. 65536 elements.
__global__ __launch_bounds__(256) void k_wfrag(const float* __restrict__ w,
                                               __hip_bfloat16* __restrict__ Afrag) {
    int i = blockIdx.x * 256 + threadIdx.x;   // 0..65535
    int ot = i >> 14, s = (i >> 9) & 31, l = (i >> 3) & 63, e = i & 7;
    int m = l & 15, quad = l >> 4;
    int o = ot * 16 + m;
    int k = s * 32 + quad * 8 + e;
    int c = k >> 4, j = k & 15;
    float v = (j < 9) ? w[o * 576 + c * 9 + j] : 0.0f;
    Afrag[i] = __float2bfloat16(v);
}

// ---------------- k_fused: taps (phase 0) + sample (phase 1) + MFMA (phase 2)
// Block = 16 px. Phase 0: per-pixel bilinear taps + blend coefs into LDS.
// Phase 1: thread (pl=tid&15, cq=tid>>4) samples 4 channels (in pairs, for
// 36 independent in-flight gathers) into E_lds[px][k=c*16+j] (bf16, padded).
// Phase 2: wave wv = o-tile, 32 MFMA steps.
// NOTE: no min-waves arg in launch_bounds — R5's (256,4) pinned VGPR=64 and
// spilled ~840 MB to scratch (FETCH 358 MB / WRITE 489 MB). Let it float.
__global__ __launch_bounds__(256) void k_fused(const float* __restrict__ inp,
                                               const float* __restrict__ off,
                                               const float* __restrict__ msk,
                                               const float* __restrict__ w8,
                                               const float* __restrict__ alpha,
                                               const __hip_bfloat16* __restrict__ Afrag,
                                               const float* __restrict__ bias,
                                               float* __restrict__ out) {
    __shared__ __attribute__((aligned(16))) char els[16 * ROWB];
    __shared__ float tapW[36][16];
    __shared__ int   tapIP[9][16];
    __shared__ float tapU[8][16];
    __shared__ float tapVV[4][16];

    const int tid = threadIdx.x;
    const int p0t = blockIdx.x * 16;

    // ---------------- phase 0: taps into LDS ----------------
    if (tid < 144) {
        int px = tid & 15, k = tid >> 4;           // k uniform per 16-thread row
        int p = p0t + px;
        int b = p >> 14, sp = p & (HWSZ - 1);
        int h = sp >> 7, w = sp & 127;
        float oy = off[(size_t)b * 18 * HWSZ + (2 * k) * HWSZ + sp];
        float ox = off[(size_t)b * 18 * HWSZ + (2 * k + 1) * HWSZ + sp];
        float m  = msk[(size_t)b * 9 * HWSZ + k * HWSZ + sp];
        float py = (float)(h + k / 3 - 1) + oy;
        float px_ = (float)(w + k % 3 - 1) + ox;
        float fy = floorf(py), fx = floorf(px_);
        float ly = py - fy, lx = px_ - fx;
        int iy0 = (int)fy, ix0 = (int)fx;
        int iy1 = iy0 + 1, ix1 = ix0 + 1;
        bool vy0 = ((unsigned)iy0 < 128u), vy1 = ((unsigned)iy1 < 128u);
        bool vx0 = ((unsigned)ix0 < 128u), vx1 = ((unsigned)ix1 < 128u);
        float hy = 1.0f - ly, hx = 1.0f - lx;
        tapW[k * 4 + 0][px] = (vy0 && vx0) ? hy * hx * m : 0.0f;
        tapW[k * 4 + 1][px] = (vy0 && vx1) ? hy * lx * m : 0.0f;
        tapW[k * 4 + 2][px] = (vy1 && vx0) ? ly * hx * m : 0.0f;
        tapW[k * 4 + 3][px] = (vy1 && vx1) ? ly * lx * m : 0.0f;
        int cy0 = min(max(iy0, 0), 127), cy1 = min(max(iy1, 0), 127);
        int cx0 = min(max(ix0, 0), 127), cx1 = min(max(ix1, 0), 127);
        int a  = min(cx0, 126);
        int s0 = cx0 - a, s1 = cx1 - a, dy = cy1 - cy0;
        tapIP[k][px] = (cy0 * 128 + a) | (dy << 14) | (s0 << 15) | (s1 << 16);
    }
    if (tid < 128) {
        int px = tid & 15, q = tid >> 4;
        int p = p0t + px;
        int b = p >> 14, sp = p & (HWSZ - 1);
        float x = w8[(size_t)b * 8 * HWSZ + q * HWSZ + sp];
        float a = alpha[q];
        tapU[q][px] = x * a;
        if ((q & 1) == 0) tapVV[q >> 1][px] = x * (1.0f - a);
    }
    __syncthreads();

    // ---------------- phase 1: sample 4 channels ----------------
    {
        const int pl = tid & 15;
        const int cq = tid >> 4;
        const int p  = p0t + pl;
        const int b  = p >> 14;

        float W00[9], W01[9], W10[9], W11[9];
        int   IPK[9];
#pragma unroll
        for (int k = 0; k < 9; k++) {
            W00[k] = tapW[k * 4 + 0][pl];
            W01[k] = tapW[k * 4 + 1][pl];
            W10[k] = tapW[k * 4 + 2][pl];
            W11[k] = tapW[k * 4 + 3][pl];
            IPK[k] = tapIP[k][pl];
        }
        float u[8], vv[4];
#pragma unroll
        for (int q = 0; q < 8; q++) u[q] = tapU[q][pl];
#pragma unroll
        for (int q = 0; q < 4; q++) vv[q] = tapVV[q][pl];

        constexpr int PINV[8][9] = {
            {0,1,2,3,4,5,6,7,8},
            {1,2,5,0,4,8,3,6,7},
            {2,5,8,1,4,7,0,3,6},
            {5,8,7,2,4,6,1,0,3},
            {8,7,6,5,4,3,2,1,0},
            {7,6,3,8,4,0,5,2,1},
            {6,3,0,7,4,1,8,5,2},
            {3,0,1,6,4,2,7,8,5}};
        const float SA = 0.5f, SB = 0.20710678f, SC = 0.08578644f;

        const float* ipb = inp + (size_t)(b * 64 + cq * 4) * HWSZ;
#pragma unroll 1
        for (int half = 0; half < 2; half++) {
            float sam2[2][9];
            // two channels' gathers issued together: 36 independent 8B loads
#pragma unroll
            for (int cc = 0; cc < 2; cc++) {
                const float* ip = ipb + (size_t)(half * 2 + cc) * HWSZ;
#pragma unroll
                for (int k = 0; k < 9; k++) {
                    int pk   = IPK[k];
                    int base = pk & 16383;
                    int dy   = (pk >> 14) & 1;
                    int s0   = (pk >> 15) & 1;
                    int s1   = (pk >> 16) & 1;
                    float2 fa, fb;
                    __builtin_memcpy(&fa, ip + base, sizeof(float2));
                    __builtin_memcpy(&fb, ip + base + (dy << 7), sizeof(float2));
                    float v00 = s0 ? fa.y : fa.x;
                    float v01 = s1 ? fa.y : fa.x;
                    float v10 = s0 ? fb.y : fb.x;
                    float v11 = s1 ? fb.y : fb.x;
                    sam2[cc][k] = W00[k] * v00 + W01[k] * v01 +
                                  W10[k] * v10 + W11[k] * v11;
                }
            }
#pragma unroll
            for (int cc = 0; cc < 2; cc++) {
                float* sam = sam2[cc];
                float A[9], Bv[9];
#pragma unroll
                for (int t = 0; t < 9; t++) {
                    float a = 0.f, bb = 0.f;
#pragma unroll
                    for (int q = 0; q < 8; q++) a += u[q] * sam[PINV[q][t]];
#pragma unroll
                    for (int i = 0; i < 4; i++) bb += vv[i] * sam[PINV[2 * i][t]];
                    A[t] = a; Bv[t] = bb;
                }
                float Ev[9];
                Ev[0] = SA * A[0] + Bv[0];
                Ev[1] = A[1] + SB * (A[0] + A[2]) + Bv[1];
                Ev[2] = SA * A[2] + Bv[2];
                Ev[3] = A[3] + SB * (A[0] + A[6]) + Bv[3];
                Ev[4] = A[4] + SC * (A[0] + A[2] + A[6] + A[8]) + Bv[4];
                Ev[5] = A[5] + SB * (A[2] + A[8]) + Bv[5];
                Ev[6] = SA * A[6] + Bv[6];
                Ev[7] = A[7] + SB * (A[6] + A[8]) + Bv[7];
                Ev[8] = SA * A[8] + Bv[8];

                int c = cq * 4 + half * 2 + cc;
                uint4 q0, q1;
                q0.x = pk2(Ev[0], Ev[1]);
                q0.y = pk2(Ev[2], Ev[3]);
                q0.z = pk2(Ev[4], Ev[5]);
                q0.w = pk2(Ev[6], Ev[7]);
                q1.x = pk2(Ev[8], 0.0f);
                q1.y = 0u; q1.z = 0u; q1.w = 0u;
                char* dst = els + pl * ROWB + c * 32;
                *(uint4*)dst = q0;
                *(uint4*)(dst + 16) = q1;
            }
        }
    }
    __syncthreads();

    // ---------------- phase 2: MFMA GEMM ----------------
    const int l    = tid & 63;
    const int wv   = tid >> 6;            // o-tile
    const int pl16 = l & 15;
    const int quad = l >> 4;

    const bf16x8* Ap = (const bf16x8*)Afrag;
    const bf16x8* Bp = (const bf16x8*)(els + pl16 * ROWB + quad * 16);

    f32x4 acc = (f32x4){0.f, 0.f, 0.f, 0.f};
    size_t ai = (size_t)(wv * 32) * 64 + l;
#pragma unroll 4
    for (int s = 0; s < 32; s++) {
        bf16x8 av = Ap[ai + (size_t)s * 64];
        bf16x8 bv = Bp[s * 4];
        acc = __builtin_amdgcn_mfma_f32_16x16x32_bf16(av, bv, acc, 0, 0, 0);
    }

    // epilogue: D row = quad*4 + r (o-offset), col = pl16 (px)
    const int pp  = p0t + pl16;
    const int bb  = pp >> 14;
    const int spp = pp & (HWSZ - 1);
    float w8v[8];
#pragma unroll
    for (int q = 0; q < 8; q++) w8v[q] = w8[(size_t)bb * 8 * HWSZ + q * HWSZ + spp];

#pragma unroll
    for (int r = 0; r < 4; r++) {
        int o = wv * 16 + quad * 4 + r;
        float bv = 0.f;
#pragma unroll
        for (int q = 0; q < 8; q++) bv += w8v[q] * bias[q * 64 + o];
        out[(size_t)(bb * 64 + o) * HWSZ + spp] = acc[r] + bv;
    }
}

// ---------------- Launch ----------------
extern "C" void kernel_launch(void* const* d_in, const int* in_sizes, int n_in,
                              void* d_out, int out_size, void* d_ws, size_t ws_size,
                              hipStream_t stream) {
    const float* input  = (const float*)d_in[0];
    const float* offset = (const float*)d_in[1];
    const float* mask   = (const float*)d_in[2];
    const float* w_c8   = (const float*)d_in[3];
    const float* weight = (const float*)d_in[4];
    const float* bias   = (const float*)d_in[5];
    const float* fc_w   = (const float*)d_in[6];
    const float* fc_b   = (const float*)d_in[7];
    float* out = (float*)d_out;
    float* wsf = (float*)d_ws;

    // ws layout (float units):
    //   Afrag bf16 [65536]   @ 0        (32768 f)
    //   pooled [128]         @ 32768
    //   alpha  [8]           @ 32896
    __hip_bfloat16* Afrag = (__hip_bfloat16*)wsf;
    float* pooled = wsf + 32768;
    float* alpha  = wsf + 32896;

    k_pool<<<dim3(128), dim3(1024), 0, stream>>>(input, pooled);
    k_r<<<dim3(1), dim3(64), 0, stream>>>(pooled, fc_w, fc_b, alpha);
    k_wfrag<<<dim3(256), dim3(256), 0, stream>>>(weight, Afrag);
    k_fused<<<dim3(2048), dim3(256), 0, stream>>>(input, offset, mask, w_c8,
                                                  alpha, Afrag, bias, out);
}

// Round 7
// 122.555 us; speedup vs baseline: 2.3925x; 1.1582x over previous
//
#include <hip/hip_runtime.h>
#include <hip/hip_bf16.h>
#include <math.h>

// Problem constants (fixed by setup_inputs): B=2, Cin=Cout=64, H=W=128
#define HWSZ 16384   // H*W
#define NPIX 32768   // B*H*W
#define ROWB 1168    // LDS E-row stride: 576 bf16 = 1152 B + 16 pad (292 dw = 4 mod 32)

typedef __attribute__((ext_vector_type(8))) short bf16x8;
typedef __attribute__((ext_vector_type(4))) float f32x4;

__device__ __forceinline__ unsigned pk2(float x, float y) {
    __hip_bfloat16 bx = __float2bfloat16(x), by = __float2bfloat16(y);
    unsigned short ux, uy;
    __builtin_memcpy(&ux, &bx, 2);
    __builtin_memcpy(&uy, &by, 2);
    return (unsigned)ux | ((unsigned)uy << 16);
}

// ---------------- k_nhwc: f32 NCHW -> bf16 NHWC, + per-(b,c) sums -----------
// Block = 64 px. Coalesced read (lanes = px), LDS transpose, coalesced pack.
// Channel sums atomically accumulated into pooled[128] (pre-zeroed by memset).
__global__ __launch_bounds__(256) void k_nhwc(const float* __restrict__ inp,
                                              __hip_bfloat16* __restrict__ inb,
                                              float* __restrict__ pooled) {
    __shared__ float ls[64 * 65];
    const int tid = threadIdx.x;
    const int p0  = blockIdx.x * 64;
    const int b   = p0 >> 14;
    const int sp0 = p0 & (HWSZ - 1);

    {   // load 64 px x 64 ch, lanes px-major (coalesced 256B)
        int px = tid & 63, cg = tid >> 6;
        const float* ip = inp + (size_t)b * 64 * HWSZ + sp0 + px;
#pragma unroll
        for (int i = 0; i < 16; i++) {
            int c = cg * 16 + i;
            ls[px * 65 + c] = ip[(size_t)c * HWSZ];
        }
    }
    __syncthreads();
    if (tid < 64) {      // channel sums for pooling
        float s = 0.f;
#pragma unroll 8
        for (int q = 0; q < 64; q++) s += ls[q * 65 + tid];
        atomicAdd(&pooled[b * 64 + tid], s);
    }
    // pack bf16 NHWC: 16B block g <-> (px = g>>3, oct = g&7); fully coalesced
    for (int g = tid; g < 512; g += 256) {
        int gpx = g >> 3, oct = g & 7;
        const float* src = &ls[gpx * 65 + oct * 8];
        uint4 d;
        d.x = pk2(src[0], src[1]);
        d.y = pk2(src[2], src[3]);
        d.z = pk2(src[4], src[5]);
        d.w = pk2(src[6], src[7]);
        *(uint4*)((char*)inb + (size_t)p0 * 128 + g * 16) = d;
    }
}

// ---------------- k_r: alpha[8] from sigmoid(fc); pooled holds SUMS ----------
__global__ void k_r(const float* __restrict__ pooled,
                    const float* __restrict__ fc_w,
                    const float* __restrict__ fc_b,
                    float* __restrict__ alpha) {
    int c = threadIdx.x;
    float s = (pooled[c] + pooled[64 + c]) * (1.0f / 16384.0f);
#pragma unroll
    for (int j = 0; j < 4; j++) {
        float v = s * fc_w[j * 64 + c];
#pragma unroll
        for (int off = 32; off; off >>= 1) v += __shfl_down(v, off, 64);
        if (c == 0) {
            float z = v + fc_b[j];
            float r = 1.0f / (1.0f + expf(-z));
            alpha[2 * j]     = r;
            alpha[2 * j + 1] = 1.0f;
        }
    }
}

// ---------------- k_wfrag: weight -> MFMA A-frag order, K=576, bf16 ----------
// Afrag[((ot*18 + s)*64 + lane)*8 + e]; lane=(quad<<4)|m; o=ot*16+m;
// k = s*32 + quad*8 + e  (k = c*9+j directly indexes w[o][k]). 36864 elems.
__global__ __launch_bounds__(256) void k_wfrag(const float* __restrict__ w,
                                               __hip_bfloat16* __restrict__ Afrag) {
    int i = blockIdx.x * 256 + threadIdx.x;   // 0..36863 (144 blocks)
    int e = i & 7, l = (i >> 3) & 63, t = i >> 9;   // t = ot*18+s, 0..71
    int ot = t / 18, s = t - ot * 18;
    int m = l & 15, quad = l >> 4;
    int o = ot * 16 + m;
    int k = s * 32 + quad * 8 + e;                   // < 576 always
    Afrag[i] = __float2bfloat16(w[o * 576 + k]);
}

// ---------------- k_fused: taps + NHWC-coalesced sample + MFMA ---------------
// Block = 16 px. Phase 1 thread = (qd=tid&15 -> 4 channels, pl=tid>>4 -> px):
// 16 consecutive lanes share a pixel, so each corner's dwordx2 loads are
// 128B-contiguous across the wave regardless of offset randomness.
__global__ __launch_bounds__(256) void k_fused(const __hip_bfloat16* __restrict__ inb,
                                               const float* __restrict__ off,
                                               const float* __restrict__ msk,
                                               const float* __restrict__ w8,
                                               const float* __restrict__ alpha,
                                               const __hip_bfloat16* __restrict__ Afrag,
                                               const float* __restrict__ bias,
                                               float* __restrict__ out) {
    __shared__ __attribute__((aligned(16))) char els[16 * ROWB];
    __shared__ float tapW[36][16];
    __shared__ int   tapIP[9][16];
    __shared__ float tapU[8][16];
    __shared__ float tapVV[4][16];

    const int tid = threadIdx.x;
    const int p0t = blockIdx.x * 16;

    // ---------------- phase 0: taps into LDS ----------------
    if (tid < 144) {
        int px = tid & 15, k = tid >> 4;
        int p = p0t + px;
        int b = p >> 14, sp = p & (HWSZ - 1);
        int h = sp >> 7, w = sp & 127;
        float oy = off[(size_t)b * 18 * HWSZ + (2 * k) * HWSZ + sp];
        float ox = off[(size_t)b * 18 * HWSZ + (2 * k + 1) * HWSZ + sp];
        float m  = msk[(size_t)b * 9 * HWSZ + k * HWSZ + sp];
        float py  = (float)(h + k / 3 - 1) + oy;
        float px_ = (float)(w + k % 3 - 1) + ox;
        float fy = floorf(py), fx = floorf(px_);
        float ly = py - fy, lx = px_ - fx;
        int iy0 = (int)fy, ix0 = (int)fx;
        int iy1 = iy0 + 1, ix1 = ix0 + 1;
        bool vy0 = ((unsigned)iy0 < 128u), vy1 = ((unsigned)iy1 < 128u);
        bool vx0 = ((unsigned)ix0 < 128u), vx1 = ((unsigned)ix1 < 128u);
        float hy = 1.0f - ly, hx = 1.0f - lx;
        tapW[k * 4 + 0][px] = (vy0 && vx0) ? hy * hx * m : 0.0f;
        tapW[k * 4 + 1][px] = (vy0 && vx1) ? hy * lx * m : 0.0f;
        tapW[k * 4 + 2][px] = (vy1 && vx0) ? ly * hx * m : 0.0f;
        tapW[k * 4 + 3][px] = (vy1 && vx1) ? ly * lx * m : 0.0f;
        int cy0 = min(max(iy0, 0), 127), cy1 = min(max(iy1, 0), 127);
        int cx0 = min(max(ix0, 0), 127), cx1 = min(max(ix1, 0), 127);
        int dx = cx1 - cx0, dy = cy1 - cy0;
        tapIP[k][px] = (cy0 * 128 + cx0) | (dy << 14) | (dx << 15);
    }
    if (tid < 128) {
        int px = tid & 15, q = tid >> 4;
        int p = p0t + px;
        int b = p >> 14, sp = p & (HWSZ - 1);
        float x = w8[(size_t)b * 8 * HWSZ + q * HWSZ + sp];
        float a = alpha[q];
        tapU[q][px] = x * a;
        if ((q & 1) == 0) tapVV[q >> 1][px] = x * (1.0f - a);
    }
    __syncthreads();

    // ---------------- phase 1: sample 4 channels (qd-major lanes) ------------
    {
        const int qd = tid & 15;          // channel quad: c = qd*4 .. qd*4+3
        const int pl = tid >> 4;          // pixel 0..15
        const int p  = p0t + pl;
        const int b  = p >> 14;
        const char* ib = (const char*)inb + (size_t)b * HWSZ * 128 + qd * 8;

        float sam[4][9];
#pragma unroll
        for (int k = 0; k < 9; k++) {
            int pk  = tapIP[k][pl];                   // LDS broadcast
            int pix = pk & 16383;
            int dy  = (pk >> 14) & 1;
            int dx  = (pk >> 15) & 1;
            int a00 = pix * 128;
            int a01 = a00 + dx * 128;
            int a10 = a00 + (dy << 14);
            int a11 = a10 + dx * 128;
            uint2 d00, d01, d10, d11;
            __builtin_memcpy(&d00, ib + a00, 8);
            __builtin_memcpy(&d01, ib + a01, 8);
            __builtin_memcpy(&d10, ib + a10, 8);
            __builtin_memcpy(&d11, ib + a11, 8);
            float w00 = tapW[k * 4 + 0][pl];
            float w01 = tapW[k * 4 + 1][pl];
            float w10 = tapW[k * 4 + 2][pl];
            float w11 = tapW[k * 4 + 3][pl];
#pragma unroll
            for (int cc = 0; cc < 4; cc++) {
                unsigned u00 = (cc & 1) ? ((cc & 2) ? d00.y & 0xffff0000u : d00.x & 0xffff0000u)
                                        : ((cc & 2) ? d00.y << 16 : d00.x << 16);
                unsigned u01 = (cc & 1) ? ((cc & 2) ? d01.y & 0xffff0000u : d01.x & 0xffff0000u)
                                        : ((cc & 2) ? d01.y << 16 : d01.x << 16);
                unsigned u10 = (cc & 1) ? ((cc & 2) ? d10.y & 0xffff0000u : d10.x & 0xffff0000u)
                                        : ((cc & 2) ? d10.y << 16 : d10.x << 16);
                unsigned u11 = (cc & 1) ? ((cc & 2) ? d11.y & 0xffff0000u : d11.x & 0xffff0000u)
                                        : ((cc & 2) ? d11.y << 16 : d11.x << 16);
                sam[cc][k] = w00 * __uint_as_float(u00) + w01 * __uint_as_float(u01) +
                             w10 * __uint_as_float(u10) + w11 * __uint_as_float(u11);
            }
        }

        float u[8], vv[4];
#pragma unroll
        for (int q = 0; q < 8; q++) u[q] = tapU[q][pl];
#pragma unroll
        for (int q = 0; q < 4; q++) vv[q] = tapVV[q][pl];

        constexpr int PINV[8][9] = {
            {0,1,2,3,4,5,6,7,8},
            {1,2,5,0,4,8,3,6,7},
            {2,5,8,1,4,7,0,3,6},
            {5,8,7,2,4,6,1,0,3},
            {8,7,6,5,4,3,2,1,0},
            {7,6,3,8,4,0,5,2,1},
            {6,3,0,7,4,1,8,5,2},
            {3,0,1,6,4,2,7,8,5}};
        const float SA = 0.5f, SB = 0.20710678f, SC = 0.08578644f;

        float ev[36];                      // 4 channels x 9 taps, bf16-packed below
#pragma unroll
        for (int cc = 0; cc < 4; cc++) {
            const float* sm = sam[cc];
            float A[9], Bv[9];
#pragma unroll
            for (int t = 0; t < 9; t++) {
                float a = 0.f, bb = 0.f;
#pragma unroll
                for (int q = 0; q < 8; q++) a += u[q] * sm[PINV[q][t]];
#pragma unroll
                for (int i = 0; i < 4; i++) bb += vv[i] * sm[PINV[2 * i][t]];
                A[t] = a; Bv[t] = bb;
            }
            float* E = ev + cc * 9;
            E[0] = SA * A[0] + Bv[0];
            E[1] = A[1] + SB * (A[0] + A[2]) + Bv[1];
            E[2] = SA * A[2] + Bv[2];
            E[3] = A[3] + SB * (A[0] + A[6]) + Bv[3];
            E[4] = A[4] + SC * (A[0] + A[2] + A[6] + A[8]) + Bv[4];
            E[5] = A[5] + SB * (A[2] + A[8]) + Bv[5];
            E[6] = SA * A[6] + Bv[6];
            E[7] = A[7] + SB * (A[6] + A[8]) + Bv[7];
            E[8] = SA * A[8] + Bv[8];
        }
        // pack 36 bf16 -> 9 x uint2, write at row pl, byte qd*72 (8B-aligned)
        char* dst = els + pl * ROWB + qd * 72;
#pragma unroll
        for (int i = 0; i < 9; i++) {
            uint2 d;
            d.x = pk2(ev[4 * i + 0], ev[4 * i + 1]);
            d.y = pk2(ev[4 * i + 2], ev[4 * i + 3]);
            *(uint2*)(dst + i * 8) = d;
        }
    }
    __syncthreads();

    // ---------------- phase 2: MFMA GEMM, K=576 -> 18 steps ------------------
    const int l    = tid & 63;
    const int wv   = tid >> 6;            // o-tile
    const int pl16 = l & 15;
    const int quad = l >> 4;

    const bf16x8* Ap = (const bf16x8*)Afrag;
    const char*   Bp = els + pl16 * ROWB + quad * 16;

    f32x4 acc = (f32x4){0.f, 0.f, 0.f, 0.f};
    size_t ai = (size_t)(wv * 18) * 64 + l;
#pragma unroll 3
    for (int s = 0; s < 18; s++) {
        bf16x8 av = Ap[ai + (size_t)s * 64];
        bf16x8 bv = *(const bf16x8*)(Bp + s * 64);
        acc = __builtin_amdgcn_mfma_f32_16x16x32_bf16(av, bv, acc, 0, 0, 0);
    }

    const int pp  = p0t + pl16;
    const int bb  = pp >> 14;
    const int spp = pp & (HWSZ - 1);
    float w8v[8];
#pragma unroll
    for (int q = 0; q < 8; q++) w8v[q] = w8[(size_t)bb * 8 * HWSZ + q * HWSZ + spp];

#pragma unroll
    for (int r = 0; r < 4; r++) {
        int o = wv * 16 + quad * 4 + r;
        float bv = 0.f;
#pragma unroll
        for (int q = 0; q < 8; q++) bv += w8v[q] * bias[q * 64 + o];
        out[(size_t)(bb * 64 + o) * HWSZ + spp] = acc[r] + bv;
    }
}

// ---------------- Launch ----------------
extern "C" void kernel_launch(void* const* d_in, const int* in_sizes, int n_in,
                              void* d_out, int out_size, void* d_ws, size_t ws_size,
                              hipStream_t stream) {
    const float* input  = (const float*)d_in[0];
    const float* offset = (const float*)d_in[1];
    const float* mask   = (const float*)d_in[2];
    const float* w_c8   = (const float*)d_in[3];
    const float* weight = (const float*)d_in[4];
    const float* bias   = (const float*)d_in[5];
    const float* fc_w   = (const float*)d_in[6];
    const float* fc_b   = (const float*)d_in[7];
    float* out = (float*)d_out;
    float* wsf = (float*)d_ws;

    // ws layout (float units):
    //   Afrag bf16 [36864]      @ 0       (18432 f)
    //   pooled [128]            @ 18432
    //   alpha  [8]              @ 18560
    //   inb bf16 NHWC [2097152] @ 18576   (4 MiB)
    __hip_bfloat16* Afrag = (__hip_bfloat16*)wsf;
    float* pooled = wsf + 18432;
    float* alpha  = wsf + 18560;
    __hip_bfloat16* inb = (__hip_bfloat16*)(wsf + 18576);

    hipMemsetAsync(pooled, 0, 128 * sizeof(float), stream);
    k_nhwc<<<dim3(512), dim3(256), 0, stream>>>(input, inb, pooled);
    k_r<<<dim3(1), dim3(64), 0, stream>>>(pooled, fc_w, fc_b, alpha);
    k_wfrag<<<dim3(144), dim3(256), 0, stream>>>(weight, Afrag);
    k_fused<<<dim3(2048), dim3(256), 0, stream>>>(inb, offset, mask, w_c8,
                                                  alpha, Afrag, bias, out);
}